// Round 1
// baseline (373.441 us; speedup 1.0000x reference)
//
#include <hip/hip_runtime.h>
#include <hip/hip_bf16.h>

#define ACT 14
#define CC 128
#define HH 256
#define EPB 182                 // edges per batch (14*13)
#define NB 2048
#define M2 (NB*EPB)             // 372736 edge-rows
#define NODES (NB*ACT)          // 28672

typedef short s16x8 __attribute__((ext_vector_type(8)));
typedef float f32x4 __attribute__((ext_vector_type(4)));

__device__ __forceinline__ short f2bf(float f) {
    unsigned u = __float_as_uint(f);
    unsigned r = (u + 0x7fffu + ((u >> 16) & 1u)) >> 16;   // RNE
    return (short)r;
}
__device__ __forceinline__ float b2f(short s) {
    return __uint_as_float(((unsigned)(unsigned short)s) << 16);
}
__device__ __forceinline__ float leaky(float x) { return x > 0.f ? x : 0.01f * x; }
__device__ __forceinline__ float softplusf(float x) { return x > 15.f ? x : log1pf(expf(x)); }

// ---------------------------------------------------------------------------
// Kernel 1: per-batch g = relu(conv_w @ (sum_i state_i)/14 + conv_b)
//           wvec[b]   = (W1L+W1R) @ g + lin1_b    (256 floats per batch)
//           also init log_prob[b] to -182*0.5*ln(2pi)
// ---------------------------------------------------------------------------
__global__ __launch_bounds__(256) void gw_kernel(
    const float* __restrict__ state, const float* __restrict__ conv_w,
    const float* __restrict__ conv_b, const float* __restrict__ lin1_w,
    const float* __restrict__ lin1_b, float* __restrict__ wvec,
    float* __restrict__ lp_out)
{
    __shared__ float ssum[CC];
    __shared__ float g[CC];
    const int b = blockIdx.x;
    const int t = threadIdx.x;

    if (t < CC) {
        float s = 0.f;
        const float* sp = state + (size_t)b * ACT * CC + t;
        #pragma unroll
        for (int i = 0; i < ACT; ++i) s += sp[i * CC];
        ssum[t] = s;
    }
    __syncthreads();
    if (t < CC) {
        float a = 0.f;
        const float* cw = conv_w + (size_t)t * CC;
        #pragma unroll 4
        for (int k = 0; k < CC; ++k) a += cw[k] * ssum[k];
        g[t] = fmaxf(a * (1.f / 14.f) + conv_b[t], 0.f);
    }
    __syncthreads();
    {
        float a = lin1_b[t];
        const float* w1 = lin1_w + (size_t)t * (2 * CC);
        #pragma unroll 4
        for (int k = 0; k < CC; ++k) a += (w1[k] + w1[CC + k]) * g[k];
        wvec[(size_t)b * HH + t] = a;
    }
    if (t == 0) lp_out[b] = -182.0f * 0.91893853320467274f; // -E*0.5*ln(2pi)
}

// ---------------------------------------------------------------------------
// Kernel 2: UV[node][0:256]   = W1L @ state[node]   (u)
//           UV[node][256:512] = W1R @ state[node]   (v)
// GEMM M=28672, K=128, N=512 (two 256-col tiles). bf16 MFMA 16x16x32.
// ---------------------------------------------------------------------------
__global__ __launch_bounds__(512) void uv_gemm(
    const float* __restrict__ state, const float* __restrict__ lin1_w,
    short* __restrict__ UV)
{
    __shared__ short As[128 * 40];   // [m][k], k contiguous, stride 40 (80B: 2-way-free banks)
    __shared__ short Bs[256 * 40];   // [n][k], k contiguous

    const int t = threadIdx.x;
    const int mbase = blockIdx.x * 128;
    const int ntile = blockIdx.y;
    const int lane = t & 63, ln = lane & 15, q = lane >> 4;
    const int wave = t >> 6, wy = wave >> 2, wx = wave & 3;

    f32x4 zero = {0.f, 0.f, 0.f, 0.f};
    f32x4 acc[4][4];
    #pragma unroll
    for (int i = 0; i < 4; ++i)
        #pragma unroll
        for (int j = 0; j < 4; ++j) acc[i][j] = zero;

    const int r = t >> 2, c8 = t & 3;
    const float* ap = state + (size_t)(mbase + r) * CC + c8 * 8;

    for (int kk = 0; kk < 4; ++kk) {            // K=128 in chunks of 32
        { // stage A: cast state to bf16
            f32x4 x0 = *(const f32x4*)(ap + kk * 32);
            f32x4 x1 = *(const f32x4*)(ap + kk * 32 + 4);
            s16x8 o;
            #pragma unroll
            for (int j = 0; j < 4; ++j) { o[j] = f2bf(x0[j]); o[4 + j] = f2bf(x1[j]); }
            *(s16x8*)&As[r * 40 + c8 * 8] = o;
        }
        // stage B: B[k][n] = W1cat[n_g][k]; store as [n][k] (= W1 rows directly)
        #pragma unroll
        for (int it = 0; it < 2; ++it) {
            int idx = t + it * 512;
            int n = idx >> 2, cb = idx & 3;
            const float* src = (ntile == 0)
                ? lin1_w + (size_t)n * (2 * CC) + kk * 32 + cb * 8
                : lin1_w + (size_t)n * (2 * CC) + CC + kk * 32 + cb * 8;
            f32x4 x0 = *(const f32x4*)src;
            f32x4 x1 = *(const f32x4*)(src + 4);
            s16x8 o;
            #pragma unroll
            for (int j = 0; j < 4; ++j) { o[j] = f2bf(x0[j]); o[4 + j] = f2bf(x1[j]); }
            *(s16x8*)&Bs[n * 40 + cb * 8] = o;
        }
        __syncthreads();
        s16x8 af[4], bfr[4];
        #pragma unroll
        for (int fr = 0; fr < 4; ++fr) af[fr] = *(s16x8*)&As[(wy * 64 + fr * 16 + ln) * 40 + q * 8];
        #pragma unroll
        for (int fc = 0; fc < 4; ++fc) bfr[fc] = *(s16x8*)&Bs[(wx * 64 + fc * 16 + ln) * 40 + q * 8];
        #pragma unroll
        for (int fr = 0; fr < 4; ++fr)
            #pragma unroll
            for (int fc = 0; fc < 4; ++fc)
                acc[fr][fc] = __builtin_amdgcn_mfma_f32_16x16x32_bf16(af[fr], bfr[fc], acc[fr][fc], 0, 0, 0);
        __syncthreads();
    }
    // epilogue: store bf16 (no bias/activation on u,v)
    #pragma unroll
    for (int fr = 0; fr < 4; ++fr)
        #pragma unroll
        for (int fc = 0; fc < 4; ++fc)
            #pragma unroll
            for (int rg = 0; rg < 4; ++rg) {
                int m = mbase + wy * 64 + fr * 16 + q * 4 + rg;
                int col = ntile * 256 + wx * 64 + fc * 16 + ln;
                UV[(size_t)m * 512 + col] = f2bf(acc[fr][fc][rg]);
            }
}

// ---------------------------------------------------------------------------
// Kernel 3: the heavy fused GEMM over 372736 edge-rows.
//   h1 = leaky(u[es] + v[ed] + w[b])    (generated into LDS per K-chunk)
//   h2 = leaky(W2 @ h1 + b2)            (MFMA, acc in regs)
//   mu/sig head dots fused in epilogue (quad shuffle-reduce), softplus,
//   action write, per-batch log_prob atomics.
// ---------------------------------------------------------------------------
__global__ __launch_bounds__(512) void edge_gemm(
    const short* __restrict__ UV, const float* __restrict__ wvec,
    const float* __restrict__ lin2_w, const float* __restrict__ lin2_b,
    const float* __restrict__ mu_w, const float* __restrict__ mu_b,
    const float* __restrict__ sig_w, const float* __restrict__ sig_b,
    const float* __restrict__ noise, const int* __restrict__ edges,
    float* __restrict__ out)
{
    __shared__ short As[128 * 40];
    __shared__ short Bs[256 * 40];
    __shared__ float mu_acc[128], sg_acc[128], lp_acc[2];

    const int t = threadIdx.x;
    const int mbase = blockIdx.x * 128;
    const int lane = t & 63, ln = lane & 15, q = lane >> 4;
    const int wave = t >> 6, wy = wave >> 2, wx = wave & 3;

    // per-thread staging row (fixed across K-loop)
    const int r = t >> 2, c8 = t & 3;
    const unsigned m = mbase + r;
    const unsigned b = m / 182u;
    const unsigned e = m - b * 182u;
    const int es = edges[2 * e], ed = edges[2 * e + 1];
    const short* up = UV + (size_t)(b * 14 + es) * 512 + c8 * 8;
    const short* vp = UV + (size_t)(b * 14 + ed) * 512 + 256 + c8 * 8;
    const float* wp = wvec + (size_t)b * 256 + c8 * 8;

    f32x4 zero = {0.f, 0.f, 0.f, 0.f};
    f32x4 acc[4][4];
    #pragma unroll
    for (int i = 0; i < 4; ++i)
        #pragma unroll
        for (int j = 0; j < 4; ++j) acc[i][j] = zero;

    for (int kk = 0; kk < 8; ++kk) {            // K=256 in chunks of 32
        { // stage A: h1 = leaky(u + v + w), cast bf16
            s16x8 u8 = *(const s16x8*)(up + kk * 32);
            s16x8 v8 = *(const s16x8*)(vp + kk * 32);
            f32x4 w0 = *(const f32x4*)(wp + kk * 32);
            f32x4 w1 = *(const f32x4*)(wp + kk * 32 + 4);
            s16x8 o;
            #pragma unroll
            for (int j = 0; j < 4; ++j) {
                float x = b2f(u8[j]) + b2f(v8[j]) + w0[j];
                o[j] = f2bf(leaky(x));
            }
            #pragma unroll
            for (int j = 0; j < 4; ++j) {
                float x = b2f(u8[4 + j]) + b2f(v8[4 + j]) + w1[j];
                o[4 + j] = f2bf(leaky(x));
            }
            *(s16x8*)&As[r * 40 + c8 * 8] = o;
        }
        // stage B: Bs[n][k] = W2[n][kk+k] cast bf16 (B[k][n] = W2[n][k])
        #pragma unroll
        for (int it = 0; it < 2; ++it) {
            int idx = t + it * 512;
            int n = idx >> 2, cb = idx & 3;
            const float* src = lin2_w + (size_t)n * 256 + kk * 32 + cb * 8;
            f32x4 x0 = *(const f32x4*)src;
            f32x4 x1 = *(const f32x4*)(src + 4);
            s16x8 o;
            #pragma unroll
            for (int j = 0; j < 4; ++j) { o[j] = f2bf(x0[j]); o[4 + j] = f2bf(x1[j]); }
            *(s16x8*)&Bs[n * 40 + cb * 8] = o;
        }
        __syncthreads();
        s16x8 af[4], bfr[4];
        #pragma unroll
        for (int fr = 0; fr < 4; ++fr) af[fr] = *(s16x8*)&As[(wy * 64 + fr * 16 + ln) * 40 + q * 8];
        #pragma unroll
        for (int fc = 0; fc < 4; ++fc) bfr[fc] = *(s16x8*)&Bs[(wx * 64 + fc * 16 + ln) * 40 + q * 8];
        #pragma unroll
        for (int fr = 0; fr < 4; ++fr)
            #pragma unroll
            for (int fc = 0; fc < 4; ++fc)
                acc[fr][fc] = __builtin_amdgcn_mfma_f32_16x16x32_bf16(af[fr], bfr[fc], acc[fr][fc], 0, 0, 0);
        __syncthreads();
    }

    // ---- fused epilogue ----
    if (t < 128) { mu_acc[t] = 0.f; sg_acc[t] = 0.f; }
    if (t < 2) lp_acc[t] = 0.f;
    __syncthreads();

    float pmu[4][4], psg[4][4];
    #pragma unroll
    for (int fr = 0; fr < 4; ++fr)
        #pragma unroll
        for (int rg = 0; rg < 4; ++rg) { pmu[fr][rg] = 0.f; psg[fr][rg] = 0.f; }

    #pragma unroll
    for (int fc = 0; fc < 4; ++fc) {
        int col = wx * 64 + fc * 16 + ln;
        float bb = lin2_b[col], mw = mu_w[col], sw = sig_w[col];
        #pragma unroll
        for (int fr = 0; fr < 4; ++fr)
            #pragma unroll
            for (int rg = 0; rg < 4; ++rg) {
                float h2 = leaky(acc[fr][fc][rg] + bb);
                pmu[fr][rg] += mw * h2;
                psg[fr][rg] += sw * h2;
            }
    }
    // reduce across the 16 lanes of each quad (cols), then LDS-accumulate per row
    #pragma unroll
    for (int fr = 0; fr < 4; ++fr)
        #pragma unroll
        for (int rg = 0; rg < 4; ++rg) {
            float a = pmu[fr][rg], s2 = psg[fr][rg];
            #pragma unroll
            for (int off = 1; off < 16; off <<= 1) {
                a  += __shfl_xor(a, off);
                s2 += __shfl_xor(s2, off);
            }
            if (ln == 0) {
                int row = wy * 64 + fr * 16 + q * 4 + rg;
                atomicAdd(&mu_acc[row], a);
                atomicAdd(&sg_acc[row], s2);
            }
        }
    __syncthreads();

    if (t < 128) {
        unsigned mm = (unsigned)mbase + t;
        unsigned bb2 = mm / 182u;
        float mu = softplusf(mu_acc[t] + mu_b[0]);
        float sd = softplusf(sg_acc[t] + sig_b[0]);
        float z = noise[mm];
        out[mm] = mu + sd * z;
        float lp = -0.5f * z * z - logf(sd);
        unsigned b0 = (unsigned)mbase / 182u;
        atomicAdd(&lp_acc[bb2 - b0], lp);
    }
    __syncthreads();
    if (t < 2) {
        unsigned b0 = (unsigned)mbase / 182u;
        if (b0 + t < (unsigned)NB) atomicAdd(&out[M2 + b0 + t], lp_acc[t]);
    }
}

// ---------------------------------------------------------------------------
extern "C" void kernel_launch(void* const* d_in, const int* in_sizes, int n_in,
                              void* d_out, int out_size, void* d_ws, size_t ws_size,
                              hipStream_t stream)
{
    const float* state  = (const float*)d_in[0];
    const float* conv_w = (const float*)d_in[1];
    const float* conv_b = (const float*)d_in[2];
    const float* lin1_w = (const float*)d_in[3];
    const float* lin1_b = (const float*)d_in[4];
    const float* lin2_w = (const float*)d_in[5];
    const float* lin2_b = (const float*)d_in[6];
    const float* mu_w   = (const float*)d_in[7];
    const float* mu_b   = (const float*)d_in[8];
    const float* sig_w  = (const float*)d_in[9];
    const float* sig_b  = (const float*)d_in[10];
    const float* noise  = (const float*)d_in[11];
    const int*   edges  = (const int*)d_in[13];
    float* out = (float*)d_out;

    float* wvec = (float*)d_ws;                                   // 2048*256 f32 = 2 MB
    short* UV   = (short*)((char*)d_ws + (size_t)NB * HH * 4);    // 28672*512 bf16 = 28 MB

    gw_kernel<<<NB, 256, 0, stream>>>(state, conv_w, conv_b, lin1_w, lin1_b, wvec, out + M2);
    uv_gemm<<<dim3(NODES / 128, 2), 512, 0, stream>>>(state, lin1_w, UV);
    edge_gemm<<<M2 / 128, 512, 0, stream>>>(UV, wvec, lin2_w, lin2_b,
                                            mu_w, mu_b, sig_w, sig_b,
                                            noise, edges, out);
}

// Round 2
// 278.227 us; speedup vs baseline: 1.3422x; 1.3422x over previous
//
#include <hip/hip_runtime.h>
#include <hip/hip_bf16.h>

#define ACT 14
#define CC 128
#define HH 256
#define EPB 182                 // edges per batch (14*13)
#define NB 2048
#define M2 (NB*EPB)             // 372736 edge-rows
#define NODES (NB*ACT)          // 28672

typedef short s16x8 __attribute__((ext_vector_type(8)));
typedef float f32x4 __attribute__((ext_vector_type(4)));

__device__ __forceinline__ short f2bf(float f) {
    unsigned u = __float_as_uint(f);
    unsigned r = (u + 0x7fffu + ((u >> 16) & 1u)) >> 16;   // RNE
    return (short)r;
}
__device__ __forceinline__ float b2f(short s) {
    return __uint_as_float(((unsigned)(unsigned short)s) << 16);
}
__device__ __forceinline__ float leaky(float x) { return fmaxf(x, 0.01f * x); }
__device__ __forceinline__ float softplusf(float x) { return x > 15.f ? x : log1pf(expf(x)); }

union bf2u { __hip_bfloat162 h; int i; short s[2]; };
__device__ __forceinline__ int pk_bf16(float a, float b) {
    bf2u u; u.h = __float22bfloat162_rn(make_float2(a, b));
    return u.i;
}

// ---------------------------------------------------------------------------
// Kernel 0 (prep): weight transposes / bf16 pre-conversions (one-time, tiny)
//   W2bf[n*256+k]  = bf16(lin2_w[n][k])                      (65536)
//   W1bf[n*128+k]  = bf16(W1L[n][k]) n<256, bf16(W1R[n-256][k]) else (65536)
//   cwT [k*128+j]  = conv_w[j][k]                            (16384)
//   w1sT[k*256+h]  = lin1_w[h][k] + lin1_w[h][128+k]         (32768)
// ---------------------------------------------------------------------------
__global__ __launch_bounds__(256) void prep_kernel(
    const float* __restrict__ conv_w, const float* __restrict__ lin1_w,
    const float* __restrict__ lin2_w, short* __restrict__ W2bf,
    short* __restrict__ W1bf, float* __restrict__ cwT, float* __restrict__ w1sT)
{
    int i = blockIdx.x * 256 + threadIdx.x;      // grid = 256 blocks -> 65536
    W2bf[i] = f2bf(lin2_w[i]);
    {
        int n = i >> 7, k = i & 127;
        float v = (n < 256) ? lin1_w[n * 256 + k] : lin1_w[(n - 256) * 256 + 128 + k];
        W1bf[i] = f2bf(v);
    }
    if (i < 16384) {
        int k = i >> 7, j = i & 127;
        cwT[i] = conv_w[j * 128 + k];
    }
    if (i < 32768) {
        int k = i >> 8, h = i & 255;
        w1sT[i] = lin1_w[h * 256 + k] + lin1_w[h * 256 + 128 + k];
    }
}

// ---------------------------------------------------------------------------
// Kernel 1: per-batch g = relu(cwT^T @ (ssum/14) + conv_b)
//           wvec[b] = w1sT^T @ g + lin1_b
// 4 batches per block; all global reads coalesced (lane = output index).
// ---------------------------------------------------------------------------
#define BPB 4
__global__ __launch_bounds__(256) void gw_kernel(
    const float* __restrict__ state, const float* __restrict__ cwT,
    const float* __restrict__ conv_b, const float* __restrict__ w1sT,
    const float* __restrict__ lin1_b, float* __restrict__ wvec,
    float* __restrict__ lp_out)
{
    __shared__ float ssum[BPB][CC];
    __shared__ float g[BPB][CC];
    const int t = threadIdx.x;
    const int b0 = blockIdx.x * BPB;

    // phase 1: per-batch state column sums (coalesced: lane = channel)
    #pragma unroll
    for (int it = 0; it < 2; ++it) {
        int idx = t + it * 256;
        int bb = idx >> 7, c = idx & 127;
        const float* sp = state + (size_t)(b0 + bb) * (ACT * CC) + c;
        float s = 0.f;
        #pragma unroll
        for (int i = 0; i < ACT; ++i) s += sp[i * CC];
        ssum[bb][c] = s * (1.f / 14.f);
    }
    __syncthreads();

    // phase 2: g[b][j] = relu(sum_k cwT[k][j] * ssum[b][k] + conv_b[j])
    {
        int j = t & 127, half = t >> 7;
        float a0 = 0.f, a1 = 0.f;
        #pragma unroll 4
        for (int k = 0; k < CC; ++k) {
            float wv = cwT[k * CC + j];          // coalesced
            a0 += wv * ssum[half * 2 + 0][k];
            a1 += wv * ssum[half * 2 + 1][k];
        }
        float cb = conv_b[j];
        g[half * 2 + 0][j] = fmaxf(a0 + cb, 0.f);
        g[half * 2 + 1][j] = fmaxf(a1 + cb, 0.f);
    }
    __syncthreads();

    // phase 3: wvec[b][h] = sum_k w1sT[k][h] * g[b][k] + lin1_b[h]
    {
        float a[BPB] = {0.f, 0.f, 0.f, 0.f};
        #pragma unroll 4
        for (int k = 0; k < CC; ++k) {
            float wv = w1sT[k * HH + t];         // coalesced
            #pragma unroll
            for (int b = 0; b < BPB; ++b) a[b] += wv * g[b][k];
        }
        float lb = lin1_b[t];
        #pragma unroll
        for (int b = 0; b < BPB; ++b)
            wvec[(size_t)(b0 + b) * HH + t] = a[b] + lb;
    }
    if (t < BPB) lp_out[b0 + t] = -182.0f * 0.91893853320467274f; // -E*0.5*ln(2pi)
}

// ---------------------------------------------------------------------------
// Kernel 2: UV[node][0:256] = W1L @ state[node], UV[node][256:512] = W1R @ ...
// GEMM M=28672, K=128, N=512 (two 256-col tiles). bf16 MFMA 16x16x32.
// ---------------------------------------------------------------------------
__global__ __launch_bounds__(512) void uv_gemm(
    const float* __restrict__ state, const short* __restrict__ W1bf,
    short* __restrict__ UV)
{
    __shared__ short As[128 * 40];
    __shared__ short Bs[256 * 40];

    const int t = threadIdx.x;
    const int mbase = blockIdx.x * 128;
    const int ntile = blockIdx.y;
    const int lane = t & 63, ln = lane & 15, q = lane >> 4;
    const int wave = t >> 6, wy = wave >> 2, wx = wave & 3;

    f32x4 zero = {0.f, 0.f, 0.f, 0.f};
    f32x4 acc[4][4];
    #pragma unroll
    for (int i = 0; i < 4; ++i)
        #pragma unroll
        for (int j = 0; j < 4; ++j) acc[i][j] = zero;

    const int r = t >> 2, c8 = t & 3;
    const float* ap = state + (size_t)(mbase + r) * CC + c8 * 8;
    const short* bp = W1bf + (size_t)(ntile * 256) * CC;

    for (int kk = 0; kk < 4; ++kk) {            // K=128 in chunks of 32
        { // stage A: cast state to bf16
            f32x4 x0 = *(const f32x4*)(ap + kk * 32);
            f32x4 x1 = *(const f32x4*)(ap + kk * 32 + 4);
            int o0 = pk_bf16(x0[0], x0[1]), o1 = pk_bf16(x0[2], x0[3]);
            int o2 = pk_bf16(x1[0], x1[1]), o3 = pk_bf16(x1[2], x1[3]);
            int* dst = (int*)&As[r * 40 + c8 * 8];
            dst[0] = o0; dst[1] = o1; dst[2] = o2; dst[3] = o3;
        }
        #pragma unroll
        for (int it = 0; it < 2; ++it) {        // stage B: pure bf16 copy
            int idx = t + it * 512;
            int n = idx >> 2, cb = idx & 3;
            s16x8 x = *(const s16x8*)(bp + n * CC + kk * 32 + cb * 8);
            *(s16x8*)&Bs[n * 40 + cb * 8] = x;
        }
        __syncthreads();
        s16x8 af[4], bfr[4];
        #pragma unroll
        for (int fr = 0; fr < 4; ++fr) af[fr] = *(s16x8*)&As[(wy * 64 + fr * 16 + ln) * 40 + q * 8];
        #pragma unroll
        for (int fc = 0; fc < 4; ++fc) bfr[fc] = *(s16x8*)&Bs[(wx * 64 + fc * 16 + ln) * 40 + q * 8];
        #pragma unroll
        for (int fr = 0; fr < 4; ++fr)
            #pragma unroll
            for (int fc = 0; fc < 4; ++fc)
                acc[fr][fc] = __builtin_amdgcn_mfma_f32_16x16x32_bf16(af[fr], bfr[fc], acc[fr][fc], 0, 0, 0);
        __syncthreads();
    }
    #pragma unroll
    for (int fr = 0; fr < 4; ++fr)
        #pragma unroll
        for (int fc = 0; fc < 4; ++fc)
            #pragma unroll
            for (int rg = 0; rg < 4; ++rg) {
                int m = mbase + wy * 64 + fr * 16 + q * 4 + rg;
                int col = ntile * 256 + wx * 64 + fc * 16 + ln;
                UV[(size_t)m * 512 + col] = f2bf(acc[fr][fc][rg]);
            }
}

// ---------------------------------------------------------------------------
// Kernel 3: fused edge GEMM, double-buffered LDS (1 barrier / k-chunk).
// ---------------------------------------------------------------------------
__global__ __launch_bounds__(512) void edge_gemm(
    const short* __restrict__ UV, const float* __restrict__ wvec,
    const short* __restrict__ W2bf, const float* __restrict__ lin2_b,
    const float* __restrict__ mu_w, const float* __restrict__ mu_b,
    const float* __restrict__ sig_w, const float* __restrict__ sig_b,
    const float* __restrict__ noise, const int* __restrict__ edges,
    float* __restrict__ out)
{
    __shared__ short As[2][128 * 40];
    __shared__ short Bs[2][256 * 40];
    __shared__ float mu_acc[128], sg_acc[128], lp_acc[2];

    const int t = threadIdx.x;
    const int mbase = blockIdx.x * 128;
    const int lane = t & 63, ln = lane & 15, q = lane >> 4;
    const int wave = t >> 6, wy = wave >> 2, wx = wave & 3;

    const int r = t >> 2, c8 = t & 3;
    const unsigned m = mbase + r;
    const unsigned b = m / 182u;
    const unsigned e = m - b * 182u;
    const int es = edges[2 * e], ed = edges[2 * e + 1];
    const short* up = UV + (size_t)(b * 14 + es) * 512 + c8 * 8;
    const short* vp = UV + (size_t)(b * 14 + ed) * 512 + 256 + c8 * 8;
    const float* wp = wvec + (size_t)b * 256 + c8 * 8;

    if (t < 128) { mu_acc[t] = 0.f; sg_acc[t] = 0.f; }
    if (t < 2) lp_acc[t] = 0.f;

    f32x4 zero = {0.f, 0.f, 0.f, 0.f};
    f32x4 acc[4][4];
    #pragma unroll
    for (int i = 0; i < 4; ++i)
        #pragma unroll
        for (int j = 0; j < 4; ++j) acc[i][j] = zero;

    // LDS addresses (fixed)
    short* a_dst0 = &As[0][r * 40 + c8 * 8];
    short* b_dst0 = &Bs[0][0];
    const int asz = 128 * 40, bsz = 256 * 40;

    auto stage = [&](int kk, int buf) {
        // A: h1 = leaky(u + v + w) -> bf16
        s16x8 u8 = *(const s16x8*)(up + kk * 32);
        s16x8 v8 = *(const s16x8*)(vp + kk * 32);
        f32x4 w0 = *(const f32x4*)(wp + kk * 32);
        f32x4 w1 = *(const f32x4*)(wp + kk * 32 + 4);
        float x0 = leaky(b2f(u8[0]) + b2f(v8[0]) + w0[0]);
        float x1 = leaky(b2f(u8[1]) + b2f(v8[1]) + w0[1]);
        float x2 = leaky(b2f(u8[2]) + b2f(v8[2]) + w0[2]);
        float x3 = leaky(b2f(u8[3]) + b2f(v8[3]) + w0[3]);
        float x4 = leaky(b2f(u8[4]) + b2f(v8[4]) + w1[0]);
        float x5 = leaky(b2f(u8[5]) + b2f(v8[5]) + w1[1]);
        float x6 = leaky(b2f(u8[6]) + b2f(v8[6]) + w1[2]);
        float x7 = leaky(b2f(u8[7]) + b2f(v8[7]) + w1[3]);
        int* dst = (int*)(a_dst0 + buf * asz);
        dst[0] = pk_bf16(x0, x1); dst[1] = pk_bf16(x2, x3);
        dst[2] = pk_bf16(x4, x5); dst[3] = pk_bf16(x6, x7);
        // B: pure bf16 copy of W2 chunk
        #pragma unroll
        for (int it = 0; it < 2; ++it) {
            int idx = t + it * 512;
            int n = idx >> 2, cb = idx & 3;
            s16x8 x = *(const s16x8*)(W2bf + n * 256 + kk * 32 + cb * 8);
            *(s16x8*)(b_dst0 + buf * bsz + n * 40 + cb * 8) = x;
        }
    };

    stage(0, 0);
    for (int kk = 0; kk < 8; ++kk) {
        int cur = kk & 1;
        __syncthreads();
        s16x8 af[4], bfr[4];
        #pragma unroll
        for (int fr = 0; fr < 4; ++fr)
            af[fr] = *(s16x8*)&As[cur][(wy * 64 + fr * 16 + ln) * 40 + q * 8];
        #pragma unroll
        for (int fc = 0; fc < 4; ++fc)
            bfr[fc] = *(s16x8*)&Bs[cur][(wx * 64 + fc * 16 + ln) * 40 + q * 8];
        if (kk < 7) stage(kk + 1, cur ^ 1);
        #pragma unroll
        for (int fr = 0; fr < 4; ++fr)
            #pragma unroll
            for (int fc = 0; fc < 4; ++fc)
                acc[fr][fc] = __builtin_amdgcn_mfma_f32_16x16x32_bf16(af[fr], bfr[fc], acc[fr][fc], 0, 0, 0);
    }

    // ---- fused epilogue ----
    __syncthreads();

    float pmu[4][4], psg[4][4];
    #pragma unroll
    for (int fr = 0; fr < 4; ++fr)
        #pragma unroll
        for (int rg = 0; rg < 4; ++rg) { pmu[fr][rg] = 0.f; psg[fr][rg] = 0.f; }

    #pragma unroll
    for (int fc = 0; fc < 4; ++fc) {
        int col = wx * 64 + fc * 16 + ln;
        float bb = lin2_b[col], mw = mu_w[col], sw = sig_w[col];
        #pragma unroll
        for (int fr = 0; fr < 4; ++fr)
            #pragma unroll
            for (int rg = 0; rg < 4; ++rg) {
                float h2 = leaky(acc[fr][fc][rg] + bb);
                pmu[fr][rg] += mw * h2;
                psg[fr][rg] += sw * h2;
            }
    }
    #pragma unroll
    for (int fr = 0; fr < 4; ++fr)
        #pragma unroll
        for (int rg = 0; rg < 4; ++rg) {
            float a = pmu[fr][rg], s2 = psg[fr][rg];
            #pragma unroll
            for (int off = 1; off < 16; off <<= 1) {
                a  += __shfl_xor(a, off);
                s2 += __shfl_xor(s2, off);
            }
            if (ln == 0) {
                int row = wy * 64 + fr * 16 + q * 4 + rg;
                atomicAdd(&mu_acc[row], a);
                atomicAdd(&sg_acc[row], s2);
            }
        }
    __syncthreads();

    if (t < 128) {
        unsigned mm = (unsigned)mbase + t;
        unsigned bb2 = mm / 182u;
        float mu = softplusf(mu_acc[t] + mu_b[0]);
        float sd = softplusf(sg_acc[t] + sig_b[0]);
        float z = noise[mm];
        out[mm] = mu + sd * z;
        float lp = -0.5f * z * z - logf(sd);
        unsigned b0 = (unsigned)mbase / 182u;
        atomicAdd(&lp_acc[bb2 - b0], lp);
    }
    __syncthreads();
    if (t < 2) {
        unsigned b0 = (unsigned)mbase / 182u;
        if (b0 + t < (unsigned)NB) atomicAdd(&out[M2 + b0 + t], lp_acc[t]);
    }
}

// ---------------------------------------------------------------------------
extern "C" void kernel_launch(void* const* d_in, const int* in_sizes, int n_in,
                              void* d_out, int out_size, void* d_ws, size_t ws_size,
                              hipStream_t stream)
{
    const float* state  = (const float*)d_in[0];
    const float* conv_w = (const float*)d_in[1];
    const float* conv_b = (const float*)d_in[2];
    const float* lin1_w = (const float*)d_in[3];
    const float* lin1_b = (const float*)d_in[4];
    const float* lin2_w = (const float*)d_in[5];
    const float* lin2_b = (const float*)d_in[6];
    const float* mu_w   = (const float*)d_in[7];
    const float* mu_b   = (const float*)d_in[8];
    const float* sig_w  = (const float*)d_in[9];
    const float* sig_b  = (const float*)d_in[10];
    const float* noise  = (const float*)d_in[11];
    const int*   edges  = (const int*)d_in[13];
    float* out = (float*)d_out;

    char* ws = (char*)d_ws;
    float* wvec = (float*)ws;                                 ws += (size_t)NB * HH * 4;          // 2 MB
    short* UV   = (short*)ws;                                 ws += (size_t)NODES * 512 * 2;      // 28 MB
    short* W2bf = (short*)ws;                                 ws += 65536 * 2;
    short* W1bf = (short*)ws;                                 ws += 65536 * 2;
    float* cwT  = (float*)ws;                                 ws += 16384 * 4;
    float* w1sT = (float*)ws;                                 ws += 32768 * 4;

    prep_kernel<<<256, 256, 0, stream>>>(conv_w, lin1_w, lin2_w, W2bf, W1bf, cwT, w1sT);
    gw_kernel<<<NB / BPB, 256, 0, stream>>>(state, cwT, conv_b, w1sT, lin1_b, wvec, out + M2);
    uv_gemm<<<dim3(NODES / 128, 2), 512, 0, stream>>>(state, W1bf, UV);
    edge_gemm<<<M2 / 128, 512, 0, stream>>>(UV, wvec, W2bf, lin2_b,
                                            mu_w, mu_b, sig_w, sig_b,
                                            noise, edges, out);
}